// Round 1
// baseline (1706.716 us; speedup 1.0000x reference)
//
#include <hip/hip_runtime.h>
#include <math.h>

// Problem constants
// feat_arm/feat_up: [16,144,64,64] f32
// off_w: [144,288,3,3], off_b: [144]
// dcn_w: [256,144,3,3], dcn_b: [256]
// out: [16,256,64,64] f32 (silu)
constexpr int BN = 16, HN = 64, WN = 64;
constexpr int C_IN = 144;        // per-feature channels (dcn input channels)
constexpr int C_CAT = 288;       // concat channels (offset conv input)
constexpr int C_OFF = 144;       // offset conv output channels
constexpr int C_OUT = 256;       // dcn output channels
constexpr int OFFG = 8, CG = 18; // offset groups, channels per group

constexpr int OFF_ELEMS   = BN * C_OFF * HN * WN;   // 9,437,184
constexpr int WTOFF_ELEMS = C_CAT * 9 * C_OFF;      // 373,248
constexpr int WTDCN_ELEMS = C_IN * 9 * C_OUT;       // 331,776

// ---------------------------------------------------------------------------
// Kernel 1: transpose weights to K-major: wT[r][co], r = ci*9 + k
// ---------------------------------------------------------------------------
__global__ __launch_bounds__(256) void transpose_w(
    const float* __restrict__ off_w, const float* __restrict__ dcn_w,
    float* __restrict__ wt_off, float* __restrict__ wt_dcn) {
  int i = blockIdx.x * 256 + threadIdx.x;
  if (i < WTOFF_ELEMS) {
    int co = i / 2592;         // off_w[co][ci][kh][kw], 2592 = 288*9
    int r  = i - co * 2592;    // r = ci*9 + k
    wt_off[r * C_OFF + co] = off_w[i];
  }
  if (i < WTDCN_ELEMS) {
    int co = i / 1296;         // dcn_w[co][c][kh][kw], 1296 = 144*9
    int r  = i - co * 1296;
    wt_dcn[r * C_OUT + co] = dcn_w[i];
  }
}

// ---------------------------------------------------------------------------
// Kernel 2: offset conv (3x3, Cin=288 concat, Cout=144, pad=1) + bias
// Block: one (b,h) row -> 144co x 64px.  Thread tile: 9co x 4px.
// Thread map: cgrp = tid>>4 (0..15, co = cgrp*9+j), pxg = tid&15 (px = pxg*4+pl)
// ---------------------------------------------------------------------------
__global__ __launch_bounds__(256) void offs_conv(
    const float* __restrict__ fa, const float* __restrict__ fu,
    const float* __restrict__ wt, const float* __restrict__ bias,
    float* __restrict__ out) {
  const int bh = blockIdx.x;
  const int b = bh >> 6;
  const int h = bh & 63;
  const int tid = threadIdx.x;
  const int cgrp = tid >> 4;   // 0..15
  const int pxg  = tid & 15;   // 0..15

  // xs: 8 input channels x 3 rows x 68 (padded row for 16B alignment; 66 used)
  __shared__ __align__(16) float xs[8][3][68];
  // wl: 72 kk x (16 cgrp x 12 padded) -- 9 weights per (kk,cgrp), b128-aligned
  __shared__ __align__(16) float wl[72][16 * 12];

  float acc[9][4];
#pragma unroll
  for (int j = 0; j < 9; ++j)
#pragma unroll
    for (int p = 0; p < 4; ++p) acc[j][p] = 0.f;

  for (int cb = 0; cb < C_CAT; cb += 8) {
    __syncthreads();  // protect LDS from previous chunk's readers
    // stage input rows h-1..h+1 for 8 channels, zero-padded
    for (int idx = tid; idx < 8 * 3 * 66; idx += 256) {
      int ci_l = idx / 198;
      int rem  = idx - ci_l * 198;
      int r    = rem / 66;
      int c    = rem - r * 66;
      int iy = h - 1 + r;
      int ix = c - 1;
      float v = 0.f;
      if (iy >= 0 && iy < 64 && ix >= 0 && ix < 64) {
        int ci = cb + ci_l;
        v = (ci < C_IN) ? fa[(((b * C_IN + ci) * 64 + iy) << 6) + ix]
                        : fu[(((b * C_IN + (ci - C_IN)) * 64 + iy) << 6) + ix];
      }
      xs[ci_l][r][c] = v;
    }
    // stage weight chunk: 72 kk x 144 co, padded per-cgrp to 12
    for (int idx = tid; idx < 72 * 144; idx += 256) {
      int kkl = idx / 144;
      int co  = idx - kkl * 144;
      int cg  = co / 9;
      int j   = co - cg * 9;
      wl[kkl][cg * 12 + j] = wt[(cb * 9 + kkl) * C_OFF + co];
    }
    __syncthreads();

    for (int ci_l = 0; ci_l < 8; ++ci_l) {
#pragma unroll
      for (int ky = 0; ky < 3; ++ky) {
        // 6-wide x window covers px(4) + kx(0..2)
        const float* xrow = &xs[ci_l][ky][pxg * 4];
        float4 xa = *(const float4*)xrow;
        float xv[6];
        xv[0] = xa.x; xv[1] = xa.y; xv[2] = xa.z; xv[3] = xa.w;
        xv[4] = xrow[4]; xv[5] = xrow[5];
#pragma unroll
        for (int kx = 0; kx < 3; ++kx) {
          int kkl = ci_l * 9 + ky * 3 + kx;
          const float4* wp4 = (const float4*)&wl[kkl][cgrp * 12];
          float4 wa = wp4[0];
          float4 wb = wp4[1];
          float w9[9] = {wa.x, wa.y, wa.z, wa.w, wb.x, wb.y, wb.z, wb.w,
                         wl[kkl][cgrp * 12 + 8]};
#pragma unroll
          for (int j = 0; j < 9; ++j)
#pragma unroll
            for (int pl = 0; pl < 4; ++pl)
              acc[j][pl] += w9[j] * xv[kx + pl];
        }
      }
    }
  }

  // epilogue: + bias, store
#pragma unroll
  for (int j = 0; j < 9; ++j) {
    int co = cgrp * 9 + j;
    float bv = bias[co];
    float4 o;
    o.x = acc[j][0] + bv;
    o.y = acc[j][1] + bv;
    o.z = acc[j][2] + bv;
    o.w = acc[j][3] + bv;
    *(float4*)&out[(((b * C_OFF + co) * 64 + h) << 6) + pxg * 4] = o;
  }
}

// ---------------------------------------------------------------------------
// Kernel 3: deformable conv (sample -> cols in LDS -> GEMM) + bias + SiLU
// Block: one (b,h) row -> 256co x 64px. Thread tile: 8co x 8px.
// cgrp = tid>>3 (0..31, co = cgrp*8+j), pxg = tid&7 (px = pxg*8+p)
// ---------------------------------------------------------------------------
__global__ __launch_bounds__(256) void dcn_silu(
    const float* __restrict__ fu, const float* __restrict__ off,
    const float* __restrict__ wt, const float* __restrict__ bias,
    float* __restrict__ out) {
  const int bh = blockIdx.x;
  const int b = bh >> 6;
  const int h = bh & 63;
  const int tid = threadIdx.x;
  const int cgrp = tid >> 3;  // 0..31
  const int pxg  = tid & 7;   // 0..7

  __shared__ __align__(16) float swc[4][9][64];   // bilinear corner weights (valid folded)
  __shared__ int s_y0[9][64];                     // raw floor(py)
  __shared__ int s_x0[9][64];                     // raw floor(px)
  __shared__ __align__(16) float cols[162][64];   // [ci_l*9+k][px] for one group

  float acc[8][8];
#pragma unroll
  for (int j = 0; j < 8; ++j)
#pragma unroll
    for (int p = 0; p < 8; ++p) acc[j][p] = 0.f;

  for (int g = 0; g < OFFG; ++g) {
    __syncthreads();  // previous iteration's phase-3 reads of cols done

    // ---- phase 1: sampling geometry per (tap k, pixel px), shared over 18 ci
    for (int idx = tid; idx < 9 * 64; idx += 256) {
      int k  = idx / 64;
      int px = idx - k * 64;
      int ky = k / 3, kx = k - ky * 3;
      int ch = (g * 9 + k) * 2;
      float oy = off[(((b * C_OFF + ch)     * 64 + h) << 6) + px];
      float ox = off[(((b * C_OFF + ch + 1) * 64 + h) << 6) + px];
      float py  = (float)(h - 1 + ky) + oy;
      float pxs = (float)(px - 1 + kx) + ox;
      float y0f = floorf(py), x0f = floorf(pxs);
      int y0 = (int)y0f, x0 = (int)x0f;
      float fy = py - y0f, fx = pxs - x0f;
      float vy0 = (y0 >= 0 && y0 < 64) ? 1.f : 0.f;
      float vy1 = (y0 + 1 >= 0 && y0 + 1 < 64) ? 1.f : 0.f;
      float vx0 = (x0 >= 0 && x0 < 64) ? 1.f : 0.f;
      float vx1 = (x0 + 1 >= 0 && x0 + 1 < 64) ? 1.f : 0.f;
      swc[0][k][px] = (1.f - fy) * (1.f - fx) * vy0 * vx0;
      swc[1][k][px] = (1.f - fy) * fx         * vy0 * vx1;
      swc[2][k][px] = fy         * (1.f - fx) * vy1 * vx0;
      swc[3][k][px] = fy         * fx         * vy1 * vx1;
      s_y0[k][px] = y0;
      s_x0[k][px] = x0;
    }
    __syncthreads();

    // ---- phase 2: gather bilinear samples into cols
    for (int idx = tid; idx < CG * 9 * 64; idx += 256) {
      int ci_l = idx / 576;
      int rem  = idx - ci_l * 576;
      int k    = rem / 64;
      int px   = rem - k * 64;
      int c = g * CG + ci_l;
      int y0 = s_y0[k][px];
      int x0 = s_x0[k][px];
      int yc0 = min(max(y0, 0), 63),     xc0 = min(max(x0, 0), 63);
      int yc1 = min(max(y0 + 1, 0), 63), xc1 = min(max(x0 + 1, 0), 63);
      const float* base = fu + (((size_t)(b * C_IN + c)) << 12);
      float v00 = base[(yc0 << 6) + xc0];
      float v01 = base[(yc0 << 6) + xc1];
      float v10 = base[(yc1 << 6) + xc0];
      float v11 = base[(yc1 << 6) + xc1];
      float val = swc[0][k][px] * v00 + swc[1][k][px] * v01 +
                  swc[2][k][px] * v10 + swc[3][k][px] * v11;
      cols[ci_l * 9 + k][px] = val;
    }
    __syncthreads();

    // ---- phase 3: GEMM over this group's 162 kk
#pragma unroll 2
    for (int kkl = 0; kkl < 162; ++kkl) {
      const float* wp = wt + (size_t)(g * 162 + kkl) * C_OUT + cgrp * 8;
      float4 w0 = *(const float4*)wp;
      float4 w1 = *(const float4*)(wp + 4);
      const float* cp = &cols[kkl][pxg * 8];
      float4 c0 = *(const float4*)cp;
      float4 c1 = *(const float4*)(cp + 4);
      float wv[8] = {w0.x, w0.y, w0.z, w0.w, w1.x, w1.y, w1.z, w1.w};
      float cv[8] = {c0.x, c0.y, c0.z, c0.w, c1.x, c1.y, c1.z, c1.w};
#pragma unroll
      for (int j = 0; j < 8; ++j)
#pragma unroll
        for (int p = 0; p < 8; ++p) acc[j][p] += wv[j] * cv[p];
    }
  }

  // ---- epilogue: bias + SiLU, store
#pragma unroll
  for (int j = 0; j < 8; ++j) {
    int co = cgrp * 8 + j;
    float bv = bias[co];
    float r[8];
#pragma unroll
    for (int p = 0; p < 8; ++p) {
      float y = acc[j][p] + bv;
      r[p] = y / (1.f + expf(-y));
    }
    float* op = &out[(((size_t)(b * C_OUT + co) * 64 + h) << 6) + pxg * 8];
    *(float4*)op       = make_float4(r[0], r[1], r[2], r[3]);
    *(float4*)(op + 4) = make_float4(r[4], r[5], r[6], r[7]);
  }
}

// ---------------------------------------------------------------------------
extern "C" void kernel_launch(void* const* d_in, const int* in_sizes, int n_in,
                              void* d_out, int out_size, void* d_ws, size_t ws_size,
                              hipStream_t stream) {
  const float* feat_arm = (const float*)d_in[0];
  const float* feat_up  = (const float*)d_in[1];
  const float* off_w    = (const float*)d_in[2];
  const float* off_b    = (const float*)d_in[3];
  const float* dcn_w    = (const float*)d_in[4];
  const float* dcn_b    = (const float*)d_in[5];
  float* out = (float*)d_out;

  float* ws     = (float*)d_ws;
  float* offbuf = ws;                               // OFF_ELEMS
  float* wtoff  = ws + OFF_ELEMS;                   // WTOFF_ELEMS
  float* wtdcn  = ws + OFF_ELEMS + WTOFF_ELEMS;     // WTDCN_ELEMS

  transpose_w<<<(WTOFF_ELEMS + 255) / 256, 256, 0, stream>>>(off_w, dcn_w, wtoff, wtdcn);
  offs_conv<<<BN * HN, 256, 0, stream>>>(feat_arm, feat_up, wtoff, off_b, offbuf);
  dcn_silu<<<BN * HN, 256, 0, stream>>>(feat_up, offbuf, wtdcn, dcn_b, out);
}

// Round 2
// 601.540 us; speedup vs baseline: 2.8372x; 2.8372x over previous
//
#include <hip/hip_runtime.h>
#include <math.h>

// feat_arm/feat_up: [16,144,64,64] f32
// off_w: [144,288,3,3], off_b: [144]
// dcn_w: [256,144,3,3], dcn_b: [256]
// out: [16,256,64,64] f32 (silu)
constexpr int BN = 16;
constexpr int C_IN = 144, C_CAT = 288, C_OFF = 144, C_OUT = 256;
constexpr int OFFG = 8, CG = 18;

constexpr int OFF_ELEMS = BN * C_OFF * 64 * 64;   // fp32 offsets in ws
constexpr int WOFF_PACK = 9 * 9 * 9 * 512;        // 373248 bf16 (cb,tap,mtile,lane,i)
constexpr int WDCN_PACK = 8 * 6 * 16 * 512;       // 393216 bf16 (g,kstep,mtile,lane,i)

typedef __attribute__((ext_vector_type(8))) short bf16x8;
typedef __attribute__((ext_vector_type(4))) float f32x4;

__device__ __forceinline__ unsigned short f2bf(float f) {
  unsigned u = __builtin_bit_cast(unsigned, f);
  return (unsigned short)((u + 0x7FFFu + ((u >> 16) & 1u)) >> 16);  // RNE, finite inputs
}

// ---------------------------------------------------------------------------
// Kernel 1: pack both weight tensors into MFMA A-fragment order (bf16).
// A-frag slot (lane, i) of a 16x32 tile: m = lane&15, k = (lane>>4)*8 + i.
// wtoff: k = ci within 32-chunk cb, per tap.  wtdcn: k = r_g = ci_l*9+tap,
// padded 162->192 with zeros (kstep 0..5).
// ---------------------------------------------------------------------------
__global__ __launch_bounds__(256) void pack_w(
    const float* __restrict__ off_w, const float* __restrict__ dcn_w,
    unsigned short* __restrict__ wo, unsigned short* __restrict__ wd) {
  int idx = blockIdx.x * 256 + threadIdx.x;
  if (idx < WOFF_PACK) {
    int i = idx & 7, lane = (idx >> 3) & 63, t = idx >> 9;
    int mt = t % 9; t /= 9;
    int tap = t % 9, cb = t / 9;
    int co = mt * 16 + (lane & 15);
    int ci = cb * 32 + ((lane >> 4) << 3) + i;
    wo[idx] = f2bf(off_w[(co * C_CAT + ci) * 9 + tap]);
  }
  if (idx < WDCN_PACK) {
    int i = idx & 7, lane = (idx >> 3) & 63, t = idx >> 9;
    int mt = t & 15; t >>= 4;
    int ks = t % 6, g = t / 6;
    int co = mt * 16 + (lane & 15);
    int r = ks * 32 + ((lane >> 4) << 3) + i;
    float v = 0.f;
    if (r < 162) {
      int ci = r / 9, tap = r - ci * 9;
      v = dcn_w[(co * C_IN + g * CG + ci) * 9 + tap];
    }
    wd[idx] = f2bf(v);
  }
}

// ---------------------------------------------------------------------------
// Kernel 2: offset conv via MFMA (9 shifted GEMMs).
// Block = (b, y-pair): out tile 144co x 128px. 4 waves, each: all 9 M-tiles
// x 2 N-tiles. Input staged in LDS as bf16 [4 rows][66 cols][32 ci] with a
// 16B-chunk XOR swizzle (chunk ^= cc&3) for balanced b128 reads AND b64
// staging writes. A-fragments straight from L2 (pre-packed).
// ---------------------------------------------------------------------------
__global__ __launch_bounds__(256) void offs_conv_mfma(
    const float* __restrict__ fa, const float* __restrict__ fu,
    const unsigned short* __restrict__ wt, const float* __restrict__ bias,
    float* __restrict__ out) {
  const int b = blockIdx.x >> 5;
  const int y0 = (blockIdx.x & 31) << 1;
  const int tid = threadIdx.x;
  const int wave = tid >> 6, lane = tid & 63;
  const int kg = lane >> 4, ln = lane & 15;

  __shared__ __align__(16) unsigned short xs[4 * 66 * 32];

  f32x4 acc[9][2];
#pragma unroll
  for (int m = 0; m < 9; ++m)
#pragma unroll
    for (int n = 0; n < 2; ++n) acc[m][n] = {0.f, 0.f, 0.f, 0.f};

  for (int cb = 0; cb < 9; ++cb) {
    __syncthreads();
    // stage 32 ci x 4 rows x 66 cols, f32 -> bf16, zero-padded at borders
    for (int idx = tid; idx < 2112; idx += 256) {
      int q = idx / 264;             // ci quad 0..7
      int rem = idx - q * 264;
      int row = rem / 66;
      int cc = rem - row * 66;       // lanes vary cc fastest -> coalesced
      int y = y0 - 1 + row, x = cc - 1;
      ushort4 wv = make_ushort4(0, 0, 0, 0);
      if (y >= 0 && y < 64 && x >= 0 && x < 64) {
        int cib = cb * 32 + (q << 2);  // quad never straddles fa/fu (144%4==0)
        const float* p = (cib < C_IN)
                             ? fa + (((size_t)(b * C_IN + cib)) << 12)
                             : fu + (((size_t)(b * C_IN + cib - C_IN)) << 12);
        int o = (y << 6) + x;
        wv.x = f2bf(p[o]);
        wv.y = f2bf(p[o + 4096]);
        wv.z = f2bf(p[o + 8192]);
        wv.w = f2bf(p[o + 12288]);
      }
      int e = ((row * 66 + cc) << 5) + (((q >> 1) ^ (cc & 3)) << 3) + ((q & 1) << 2);
      *(ushort4*)&xs[e] = wv;
    }
    __syncthreads();

    for (int tap = 0; tap < 9; ++tap) {
      const int ky = tap / 3, kx = tap - ky * 3;
      bf16x8 a[9];
      const unsigned short* wp = wt + (((size_t)(cb * 9 + tap) * 9) << 9) + (lane << 3);
#pragma unroll
      for (int m = 0; m < 9; ++m) a[m] = *(const bf16x8*)(wp + (m << 9));
#pragma unroll
      for (int n = 0; n < 2; ++n) {
        int px = ((wave << 1) + n) * 16 + ln;           // 0..127
        int row = (px >> 6) + ky, cc = (px & 63) + kx;  // shifted window
        int e = ((row * 66 + cc) << 5) + ((kg ^ (cc & 3)) << 3);
        bf16x8 bv = *(const bf16x8*)&xs[e];
#pragma unroll
        for (int m = 0; m < 9; ++m)
          acc[m][n] = __builtin_amdgcn_mfma_f32_16x16x32_bf16(a[m], bv, acc[m][n], 0, 0, 0);
      }
    }
  }

  // epilogue: C/D layout col=lane&15 (px), row=(lane>>4)*4+r (co)
#pragma unroll
  for (int n = 0; n < 2; ++n) {
    int px = ((wave << 1) + n) * 16 + ln;
    int y = y0 + (px >> 6), x = px & 63;
#pragma unroll
    for (int m = 0; m < 9; ++m) {
      int cob = m * 16 + (kg << 2);
#pragma unroll
      for (int r = 0; r < 4; ++r)
        out[(((size_t)(b * C_OFF + cob + r)) << 12) + (y << 6) + x] =
            acc[m][n][r] + bias[cob + r];
    }
  }
}

// ---------------------------------------------------------------------------
// Kernel 3: deformable conv via MFMA + bias + SiLU.
// Block = (b,h): out tile 256co x 64px. 4 waves split M (4 M-tiles each, all
// 4 N-tiles) so A-frags are loaded once per block. Per group: geometry ->
// cols (bf16, K-contiguous per px: colsT[64][208], rows 162..191 zeroed) ->
// 6 MFMA K-steps.
// ---------------------------------------------------------------------------
__global__ __launch_bounds__(256) void dcn_mfma(
    const float* __restrict__ fu, const float* __restrict__ off,
    const unsigned short* __restrict__ wt, const float* __restrict__ bias,
    float* __restrict__ out) {
  const int b = blockIdx.x >> 6, h = blockIdx.x & 63;
  const int tid = threadIdx.x;
  const int wave = tid >> 6, lane = tid & 63;
  const int kg = lane >> 4, ln = lane & 15;

  __shared__ float swc[4 * 9 * 68];   // corner weights, px-dim padded to 68
  __shared__ int s_y0[9 * 68], s_x0[9 * 68];
  __shared__ __align__(16) unsigned short colsT[64 * 208];

  f32x4 acc[4][4];
#pragma unroll
  for (int mi = 0; mi < 4; ++mi)
#pragma unroll
    for (int nt = 0; nt < 4; ++nt) acc[mi][nt] = {0.f, 0.f, 0.f, 0.f};

  // zero cols once: pad rows 162..191 must be 0 (not poison/NaN) for MFMA
  for (int i = tid; i < 64 * 104; i += 256) ((unsigned int*)colsT)[i] = 0u;

  for (int g = 0; g < OFFG; ++g) {
    __syncthreads();
    // ---- phase 1: sampling geometry per (tap, px), shared across 18 ci
    for (int idx = tid; idx < 576; idx += 256) {
      int k = idx >> 6, px = idx & 63;
      int ky = k / 3, kx = k - ky * 3;
      int ch = (g * 9 + k) * 2;
      float oy = off[(((size_t)(b * C_OFF + ch)) << 12) + (h << 6) + px];
      float ox = off[(((size_t)(b * C_OFF + ch + 1)) << 12) + (h << 6) + px];
      float py = (float)(h - 1 + ky) + oy;
      float pxs = (float)(px - 1 + kx) + ox;
      float y0f = floorf(py), x0f = floorf(pxs);
      int y0 = (int)y0f, x0 = (int)x0f;
      float fy = py - y0f, fx = pxs - x0f;
      float vy0 = (y0 >= 0 && y0 < 64) ? 1.f : 0.f;
      float vy1 = (y0 + 1 >= 0 && y0 + 1 < 64) ? 1.f : 0.f;
      float vx0 = (x0 >= 0 && x0 < 64) ? 1.f : 0.f;
      float vx1 = (x0 + 1 >= 0 && x0 + 1 < 64) ? 1.f : 0.f;
      int kb = k * 68 + px;
      swc[0 * 612 + kb] = (1.f - fy) * (1.f - fx) * vy0 * vx0;
      swc[1 * 612 + kb] = (1.f - fy) * fx * vy0 * vx1;
      swc[2 * 612 + kb] = fy * (1.f - fx) * vy1 * vx0;
      swc[3 * 612 + kb] = fy * fx * vy1 * vx1;
      s_y0[kb] = y0;
      s_x0[kb] = x0;
    }
    __syncthreads();
    // ---- phase 2: bilinear gather -> colsT[px][r], r = ci_l*9 + tap
    for (int idx = tid; idx < 10368; idx += 256) {
      int px = idx / 162;
      int r = idx - px * 162;         // lanes vary r fastest -> 2-way writes
      int ci = r / 9, k = r - ci * 9;
      int kb = k * 68 + px;
      int y0 = s_y0[kb], x0 = s_x0[kb];
      int yc0 = min(max(y0, 0), 63), xc0 = min(max(x0, 0), 63);
      int yc1 = min(max(y0 + 1, 0), 63), xc1 = min(max(x0 + 1, 0), 63);
      const float* base = fu + (((size_t)(b * C_IN + g * CG + ci)) << 12);
      float v = swc[0 * 612 + kb] * base[(yc0 << 6) + xc0] +
                swc[1 * 612 + kb] * base[(yc0 << 6) + xc1] +
                swc[2 * 612 + kb] * base[(yc1 << 6) + xc0] +
                swc[3 * 612 + kb] * base[(yc1 << 6) + xc1];
      colsT[px * 208 + r] = f2bf(v);
    }
    __syncthreads();
    // ---- phase 3: 6 MFMA K-steps of 32 over this group's 192 (padded) k
    for (int ks = 0; ks < 6; ++ks) {
      bf16x8 a[4];
      const unsigned short* wp =
          wt + ((((size_t)(g * 6 + ks) * 16 + (wave << 2)) << 6) + lane) * 8;
#pragma unroll
      for (int mi = 0; mi < 4; ++mi) a[mi] = *(const bf16x8*)(wp + (mi << 9));
#pragma unroll
      for (int nt = 0; nt < 4; ++nt) {
        bf16x8 bv = *(const bf16x8*)&colsT[(nt * 16 + ln) * 208 + ks * 32 + (kg << 3)];
#pragma unroll
        for (int mi = 0; mi < 4; ++mi)
          acc[mi][nt] = __builtin_amdgcn_mfma_f32_16x16x32_bf16(a[mi], bv, acc[mi][nt], 0, 0, 0);
      }
    }
  }

  // ---- epilogue: bias + SiLU
#pragma unroll
  for (int mi = 0; mi < 4; ++mi) {
    int cob = ((wave << 2) + mi) * 16 + (kg << 2);
#pragma unroll
    for (int nt = 0; nt < 4; ++nt) {
      int px = nt * 16 + ln;
#pragma unroll
      for (int r = 0; r < 4; ++r) {
        float y = acc[mi][nt][r] + bias[cob + r];
        out[(((size_t)(b * C_OUT + cob + r)) << 12) + (h << 6) + px] =
            y / (1.f + expf(-y));
      }
    }
  }
}

// ---------------------------------------------------------------------------
extern "C" void kernel_launch(void* const* d_in, const int* in_sizes, int n_in,
                              void* d_out, int out_size, void* d_ws, size_t ws_size,
                              hipStream_t stream) {
  const float* feat_arm = (const float*)d_in[0];
  const float* feat_up  = (const float*)d_in[1];
  const float* off_w    = (const float*)d_in[2];
  const float* off_b    = (const float*)d_in[3];
  const float* dcn_w    = (const float*)d_in[4];
  const float* dcn_b    = (const float*)d_in[5];
  float* out = (float*)d_out;

  float* ws = (float*)d_ws;
  float* offbuf = ws;                                        // OFF_ELEMS f32
  unsigned short* wo = (unsigned short*)(ws + OFF_ELEMS);    // WOFF_PACK bf16
  unsigned short* wd = wo + WOFF_PACK;                       // WDCN_PACK bf16

  pack_w<<<(WDCN_PACK + 255) / 256, 256, 0, stream>>>(off_w, dcn_w, wo, wd);
  offs_conv_mfma<<<BN * 32, 256, 0, stream>>>(feat_arm, feat_up, wo, off_b, offbuf);
  dcn_mfma<<<BN * 64, 256, 0, stream>>>(feat_up, offbuf, wd, dcn_b, out);
}

// Round 3
// 410.872 us; speedup vs baseline: 4.1539x; 1.4641x over previous
//
#include <hip/hip_runtime.h>
#include <math.h>

// feat_arm/feat_up: [16,144,64,64] f32
// off_w: [144,288,3,3], off_b: [144]
// dcn_w: [256,144,3,3], dcn_b: [256]
// out: [16,256,64,64] f32 (silu)
constexpr int BN = 16;
constexpr int C_IN = 144, C_CAT = 288, C_OFF = 144, C_OUT = 256;
constexpr int OFFG = 8, CG = 18;

constexpr int OFF_ELEMS = BN * C_OFF * 64 * 64;   // fp32 offsets in ws
constexpr int WOFF_PACK = 9 * 9 * 9 * 512;        // 373248 bf16 (cb,tap,mtile,lane,i)
constexpr int WDCN_PACK = 8 * 6 * 16 * 512;       // 393216 bf16 (t=g*6+ks, mtile, lane, i)

typedef __attribute__((ext_vector_type(8))) short bf16x8;
typedef __attribute__((ext_vector_type(4))) float f32x4;

__device__ __forceinline__ unsigned short f2bf(float f) {
  unsigned u = __builtin_bit_cast(unsigned, f);
  return (unsigned short)((u + 0x7FFFu + ((u >> 16) & 1u)) >> 16);  // RNE, finite inputs
}

__device__ __forceinline__ unsigned packh2(float a, float b) {
  unsigned short ha = __builtin_bit_cast(unsigned short, (_Float16)a);
  unsigned short hb = __builtin_bit_cast(unsigned short, (_Float16)b);
  return (unsigned)ha | ((unsigned)hb << 16);
}
__device__ __forceinline__ float h2f_lo(unsigned u) {
  return (float)__builtin_bit_cast(_Float16, (unsigned short)(u & 0xFFFFu));
}
__device__ __forceinline__ float h2f_hi(unsigned u) {
  return (float)__builtin_bit_cast(_Float16, (unsigned short)(u >> 16));
}

// async global->LDS, 16B per lane, wave-uniform LDS base
__device__ __forceinline__ void gload_lds16(const unsigned short* g, unsigned short* l) {
  __builtin_amdgcn_global_load_lds(
      (const __attribute__((address_space(1))) unsigned*)g,
      (__attribute__((address_space(3))) unsigned*)l, 16, 0, 0);
}

// ---------------------------------------------------------------------------
// Kernel 1: pack both weight tensors into MFMA A-fragment order (bf16).
// A-frag slot (lane, i) of a 16x32 tile: m = lane&15, k = (lane>>4)*8 + i.
// ---------------------------------------------------------------------------
__global__ __launch_bounds__(256) void pack_w(
    const float* __restrict__ off_w, const float* __restrict__ dcn_w,
    unsigned short* __restrict__ wo, unsigned short* __restrict__ wd) {
  int idx = blockIdx.x * 256 + threadIdx.x;
  if (idx < WOFF_PACK) {
    int i = idx & 7, lane = (idx >> 3) & 63, t = idx >> 9;
    int mt = t % 9; t /= 9;
    int tap = t % 9, cb = t / 9;
    int co = mt * 16 + (lane & 15);
    int ci = cb * 32 + ((lane >> 4) << 3) + i;
    wo[idx] = f2bf(off_w[(co * C_CAT + ci) * 9 + tap]);
  }
  if (idx < WDCN_PACK) {
    int i = idx & 7, lane = (idx >> 3) & 63, t = idx >> 9;
    int mt = t & 15; t >>= 4;
    int ks = t % 6, g = t / 6;
    int co = mt * 16 + (lane & 15);
    int r = ks * 32 + ((lane >> 4) << 3) + i;
    float v = 0.f;
    if (r < 162) {
      int ci = r / 9, tap = r - ci * 9;
      v = dcn_w[(co * C_IN + g * CG + ci) * 9 + tap];
    }
    wd[idx] = f2bf(v);
  }
}

// ---------------------------------------------------------------------------
// Kernel 2: offset conv via MFMA (9 shifted GEMMs). Unchanged from round 2.
// ---------------------------------------------------------------------------
__global__ __launch_bounds__(256) void offs_conv_mfma(
    const float* __restrict__ fa, const float* __restrict__ fu,
    const unsigned short* __restrict__ wt, const float* __restrict__ bias,
    float* __restrict__ out) {
  const int b = blockIdx.x >> 5;
  const int y0 = (blockIdx.x & 31) << 1;
  const int tid = threadIdx.x;
  const int wave = tid >> 6, lane = tid & 63;
  const int kg = lane >> 4, ln = lane & 15;

  __shared__ __align__(16) unsigned short xs[4 * 66 * 32];

  f32x4 acc[9][2];
#pragma unroll
  for (int m = 0; m < 9; ++m)
#pragma unroll
    for (int n = 0; n < 2; ++n) acc[m][n] = {0.f, 0.f, 0.f, 0.f};

  for (int cb = 0; cb < 9; ++cb) {
    __syncthreads();
    for (int idx = tid; idx < 2112; idx += 256) {
      int q = idx / 264;
      int rem = idx - q * 264;
      int row = rem / 66;
      int cc = rem - row * 66;
      int y = y0 - 1 + row, x = cc - 1;
      ushort4 wv = make_ushort4(0, 0, 0, 0);
      if (y >= 0 && y < 64 && x >= 0 && x < 64) {
        int cib = cb * 32 + (q << 2);
        const float* p = (cib < C_IN)
                             ? fa + (((size_t)(b * C_IN + cib)) << 12)
                             : fu + (((size_t)(b * C_IN + cib - C_IN)) << 12);
        int o = (y << 6) + x;
        wv.x = f2bf(p[o]);
        wv.y = f2bf(p[o + 4096]);
        wv.z = f2bf(p[o + 8192]);
        wv.w = f2bf(p[o + 12288]);
      }
      int e = ((row * 66 + cc) << 5) + (((q >> 1) ^ (cc & 3)) << 3) + ((q & 1) << 2);
      *(ushort4*)&xs[e] = wv;
    }
    __syncthreads();

    for (int tap = 0; tap < 9; ++tap) {
      const int ky = tap / 3, kx = tap - ky * 3;
      bf16x8 a[9];
      const unsigned short* wp = wt + (((size_t)(cb * 9 + tap) * 9) << 9) + (lane << 3);
#pragma unroll
      for (int m = 0; m < 9; ++m) a[m] = *(const bf16x8*)(wp + (m << 9));
#pragma unroll
      for (int n = 0; n < 2; ++n) {
        int px = ((wave << 1) + n) * 16 + ln;
        int row = (px >> 6) + ky, cc = (px & 63) + kx;
        int e = ((row * 66 + cc) << 5) + ((kg ^ (cc & 3)) << 3);
        bf16x8 bv = *(const bf16x8*)&xs[e];
#pragma unroll
        for (int m = 0; m < 9; ++m)
          acc[m][n] = __builtin_amdgcn_mfma_f32_16x16x32_bf16(a[m], bv, acc[m][n], 0, 0, 0);
      }
    }
  }

#pragma unroll
  for (int n = 0; n < 2; ++n) {
    int px = ((wave << 1) + n) * 16 + ln;
    int y = y0 + (px >> 6), x = px & 63;
#pragma unroll
    for (int m = 0; m < 9; ++m) {
      int cob = m * 16 + (kg << 2);
#pragma unroll
      for (int r = 0; r < 4; ++r)
        out[(((size_t)(b * C_OFF + cob + r)) << 12) + (y << 6) + x] =
            acc[m][n][r] + bias[cob + r];
    }
  }
}

// ---------------------------------------------------------------------------
// Kernel 3: deformable conv via MFMA, gather-direct-to-register B-fragments.
// Block = (b,h): 256co x 64px. 4 waves SPLIT N: wave w owns px = w*16+ln.
// Per group: geometry packed once per (tap,px) into 16B LDS entries
// (clamped corner offsets u16x4 + fp16 weights, validity folded).
// Per K-step (32): each lane builds its B-frag (8 bilinear samples) in
// registers, then 16 MFMAs against LDS-staged A-fragments (global_load_lds,
// double-buffered, stage issued right after barrier -> latency hidden).
// k in [162,192) contributes 0 via zeroed A-pack (ci clamped for safety).
// ---------------------------------------------------------------------------
__global__ __launch_bounds__(256, 3) void dcn_mfma(
    const float* __restrict__ fu, const float* __restrict__ off,
    const unsigned short* __restrict__ wt, const float* __restrict__ bias,
    float* __restrict__ out) {
  const int b = blockIdx.x >> 6, h = blockIdx.x & 63;
  const int tid = threadIdx.x;
  const int wave = tid >> 6, lane = tid & 63;
  const int kg = lane >> 4, ln = lane & 15;
  const int px = (wave << 4) + ln;   // this wave's pixel (n index)

  __shared__ __align__(16) uint4 geo[576];             // [tap*64+px], 9.2KB
  __shared__ __align__(16) unsigned short wl[2][8192]; // A chunks, 2x16KB

  f32x4 acc[16];
#pragma unroll
  for (int m = 0; m < 16; ++m) acc[m] = {0.f, 0.f, 0.f, 0.f};

  // prologue: stage A chunk t=0 into buffer 0
  {
    const unsigned short* src = wt + (size_t)(wave * 4) * 512 + lane * 8;
#pragma unroll
    for (int j = 0; j < 4; ++j)
      gload_lds16(src + j * 512, &wl[0][(wave * 4 + j) * 512]);
  }

  int t = 0;
  for (int g = 0; g < OFFG; ++g) {
    __syncthreads();  // protect geo from previous group's readers
    // ---- geometry per (tap, px): 576 packed entries
    for (int idx = tid; idx < 576; idx += 256) {
      int tap = idx >> 6, p = idx & 63;
      int ky = tap / 3, kx = tap - ky * 3;
      int ch = (g * 9 + tap) * 2;
      float oy = off[(((size_t)(b * C_OFF + ch)) << 12) + (h << 6) + p];
      float ox = off[(((size_t)(b * C_OFF + ch + 1)) << 12) + (h << 6) + p];
      float py = (float)(h - 1 + ky) + oy;
      float pxs = (float)(p - 1 + kx) + ox;
      float y0f = floorf(py), x0f = floorf(pxs);
      int y0 = (int)y0f, x0 = (int)x0f;
      float fy = py - y0f, fx = pxs - x0f;
      float vy0 = (y0 >= 0 && y0 < 64) ? 1.f : 0.f;
      float vy1 = (y0 + 1 >= 0 && y0 + 1 < 64) ? 1.f : 0.f;
      float vx0 = (x0 >= 0 && x0 < 64) ? 1.f : 0.f;
      float vx1 = (x0 + 1 >= 0 && x0 + 1 < 64) ? 1.f : 0.f;
      int yc0 = min(max(y0, 0), 63), xc0 = min(max(x0, 0), 63);
      int yc1 = min(max(y0 + 1, 0), 63), xc1 = min(max(x0 + 1, 0), 63);
      uint4 gg;
      gg.x = (unsigned)((yc0 << 6) + xc0) | ((unsigned)((yc0 << 6) + xc1) << 16);
      gg.y = (unsigned)((yc1 << 6) + xc0) | ((unsigned)((yc1 << 6) + xc1) << 16);
      gg.z = packh2((1.f - fy) * (1.f - fx) * vy0 * vx0,
                    (1.f - fy) * fx * vy0 * vx1);
      gg.w = packh2(fy * (1.f - fx) * vy1 * vx0,
                    fy * fx * vy1 * vx1);
      geo[idx] = gg;
    }
    __syncthreads();

    const float* gbase = fu + (((size_t)(b * C_IN + g * CG)) << 12);
    for (int ks = 0; ks < 6; ++ks, ++t) {
      // ---- build B fragment in registers: 8 bilinear samples at this px
      bf16x8 bv;
#pragma unroll
      for (int i = 0; i < 8; ++i) {
        int r = ks * 32 + (kg << 3) + i;
        int ci = r / 9;
        int tap = r - ci * 9;
        ci = ci < CG ? ci : CG - 1;  // pad rows: A is zero there, keep in-bounds
        uint4 gg = geo[(tap << 6) + px];
        const float* pl = gbase + ((size_t)ci << 12);
        float v00 = pl[gg.x & 0xFFFFu];
        float v01 = pl[gg.x >> 16];
        float v10 = pl[gg.y & 0xFFFFu];
        float v11 = pl[gg.y >> 16];
        float s = h2f_lo(gg.z) * v00 + h2f_hi(gg.z) * v01 +
                  h2f_lo(gg.w) * v10 + h2f_hi(gg.w) * v11;
        bv[i] = (short)f2bf(s);
      }

      __syncthreads();  // stage(t) visible (vmcnt0), prev MFMA reads done

      // ---- issue stage(t+1) into the other buffer (readers done pre-barrier)
      if (t < 47) {
        const unsigned short* src =
            wt + (size_t)(t + 1) * 8192 + (wave * 4) * 512 + lane * 8;
        unsigned short* dst = wl[(t + 1) & 1];
#pragma unroll
        for (int j = 0; j < 4; ++j)
          gload_lds16(src + j * 512, dst + (wave * 4 + j) * 512);
      }

      // ---- 16 MFMAs: all M-tiles against this wave's B fragment
      const unsigned short* wbuf = wl[t & 1] + lane * 8;
#pragma unroll
      for (int mt = 0; mt < 16; ++mt) {
        bf16x8 av = *(const bf16x8*)(wbuf + mt * 512);
        acc[mt] = __builtin_amdgcn_mfma_f32_16x16x32_bf16(av, bv, acc[mt], 0, 0, 0);
      }
    }
  }

  // ---- epilogue: bias + SiLU.  C/D: col(px)=lane&15, row=kg*4+r
#pragma unroll
  for (int mt = 0; mt < 16; ++mt) {
    int cob = mt * 16 + (kg << 2);
#pragma unroll
    for (int r = 0; r < 4; ++r) {
      float y = acc[mt][r] + bias[cob + r];
      out[(((size_t)(b * C_OUT + cob + r)) << 12) + (h << 6) + px] =
          y / (1.f + expf(-y));
    }
  }
}

// ---------------------------------------------------------------------------
extern "C" void kernel_launch(void* const* d_in, const int* in_sizes, int n_in,
                              void* d_out, int out_size, void* d_ws, size_t ws_size,
                              hipStream_t stream) {
  const float* feat_arm = (const float*)d_in[0];
  const float* feat_up  = (const float*)d_in[1];
  const float* off_w    = (const float*)d_in[2];
  const float* off_b    = (const float*)d_in[3];
  const float* dcn_w    = (const float*)d_in[4];
  const float* dcn_b    = (const float*)d_in[5];
  float* out = (float*)d_out;

  float* ws = (float*)d_ws;
  float* offbuf = ws;                                        // OFF_ELEMS f32
  unsigned short* wo = (unsigned short*)(ws + OFF_ELEMS);    // WOFF_PACK bf16
  unsigned short* wd = wo + WOFF_PACK;                       // WDCN_PACK bf16

  pack_w<<<(WDCN_PACK + 255) / 256, 256, 0, stream>>>(off_w, dcn_w, wo, wd);
  offs_conv_mfma<<<BN * 32, 256, 0, stream>>>(feat_arm, feat_up, wo, off_b, offbuf);
  dcn_mfma<<<BN * 64, 256, 0, stream>>>(feat_up, offbuf, wd, dcn_b, out);
}